// Round 3
// baseline (177.742 us; speedup 1.0000x reference)
//
#include <hip/hip_runtime.h>
#include <math.h>

#define EPS_N 1e-12f
#define MARGIN 0.3f
#define INF_BITS 0x7f800000u
#define NCLS 128     // label space (randint(0,128))
#define D 512
#define PADR 256     // padded rows after fh so banded staging can over-read safely

typedef __attribute__((ext_vector_type(8))) short short8;   // 8 bf16 = 4 VGPRs
typedef __attribute__((ext_vector_type(4))) float float4v;  // MFMA 16x16 accum

__device__ __forceinline__ unsigned short f2bf(float f) {   // RNE bf16
    unsigned u = __float_as_uint(f);
    u += 0x7fff + ((u >> 16) & 1);
    return (unsigned short)(u >> 16);
}
__device__ __forceinline__ void gl16(const void* g, void* l) {
    // 16B async global->LDS; global addr per-lane, LDS dest = uniform base + lane*16
    __builtin_amdgcn_global_load_lds((const __attribute__((address_space(1))) void*)g,
                                     (__attribute__((address_space(3))) void*)l, 16, 0, 0);
}

// ---------------------------------------------------------------------------
// K0: one-block bucketing, coalesced-metadata (unchanged).
// ---------------------------------------------------------------------------
__global__ __launch_bounds__(1024) void k_bucket(const int* __restrict__ lab, int Bn,
        int* __restrict__ pos, int* __restrict__ labp,
        int* __restrict__ cstart_g, int* __restrict__ ccnt_g,
        float* __restrict__ meanpos, float* __restrict__ pcinv,
        int* __restrict__ poscnt, unsigned* __restrict__ minbits) {
    __shared__ int cnt[NCLS], cs[NCLS + 1], off[NCLS], sa[NCLS], sb[NCLS];
    int tid = threadIdx.x;
    if (tid < NCLS) cnt[tid] = 0;
    __syncthreads();
    for (int i = tid; i < Bn; i += 1024) atomicAdd(&cnt[lab[i] & (NCLS - 1)], 1);
    __syncthreads();
    if (tid < NCLS) sa[tid] = cnt[tid];
    __syncthreads();
    int* src = sa; int* dst = sb;
    for (int ofs = 1; ofs < NCLS; ofs <<= 1) {          // Hillis-Steele inclusive
        if (tid < NCLS) dst[tid] = src[tid] + ((tid >= ofs) ? src[tid - ofs] : 0);
        __syncthreads();
        int* t = src; src = dst; dst = t;
    }
    if (tid < NCLS) {
        int ex = src[tid] - cnt[tid];                   // exclusive
        cs[tid] = ex;
        off[tid] = ex;
        cstart_g[tid] = ex;
        ccnt_g[tid] = cnt[tid];
    }
    if (tid == 0) cs[NCLS] = Bn;
    __syncthreads();
    // coalesced per-slot metadata: class(p) = largest l with cs[l] <= p
    for (int p = tid; p < Bn; p += 1024) {
        int lo = 0, hi = NCLS - 1;
        #pragma unroll
        for (int s = 0; s < 7; ++s) {
            int mid = (lo + hi + 1) >> 1;
            if (cs[mid] <= p) lo = mid; else hi = mid - 1;
        }
        int l = lo, m = cnt[l];
        labp[p] = l;
        poscnt[p] = m;
        pcinv[p] = 1.0f / (float)m;
        meanpos[p] = 0.f;          // accumulates raw dist-sums (posband3)
        minbits[p] = INF_BITS;
    }
    // pos scatter (reads coalesced; only pos[] store is scattered-by-class)
    for (int i = tid; i < Bn; i += 1024) {
        int l = lab[i] & (NCLS - 1);
        pos[i] = atomicAdd(&off[l], 1);
    }
}

// ---------------------------------------------------------------------------
// K1: normalize; one wave per row, no __syncthreads (unchanged).
// ---------------------------------------------------------------------------
__global__ __launch_bounds__(256) void k_normalize(const float* __restrict__ x,
        const int* __restrict__ pos, unsigned short* __restrict__ fh,
        float* __restrict__ sqp) {
    int w = threadIdx.x >> 6, L = threadIdx.x & 63;
    int row = blockIdx.x * 4 + w;
    const float* xr = x + (size_t)row * D + L * 8;
    float4 a = *(const float4*)xr;
    float4 b = *(const float4*)(xr + 4);
    float ss = a.x * a.x;
    ss = fmaf(a.y, a.y, ss); ss = fmaf(a.z, a.z, ss); ss = fmaf(a.w, a.w, ss);
    ss = fmaf(b.x, b.x, ss); ss = fmaf(b.y, b.y, ss);
    ss = fmaf(b.z, b.z, ss); ss = fmaf(b.w, b.w, ss);
    #pragma unroll
    for (int off = 32; off; off >>= 1) ss += __shfl_xor(ss, off, 64);
    float inv = 1.0f / fmaxf(sqrtf(ss), EPS_N);
    int prow = pos[row];
    if (L == 0) sqp[prow] = ss * inv * inv;
    ushort4 h0, h1;
    h0.x = f2bf(a.x * inv); h0.y = f2bf(a.y * inv);
    h0.z = f2bf(a.z * inv); h0.w = f2bf(a.w * inv);
    h1.x = f2bf(b.x * inv); h1.y = f2bf(b.y * inv);
    h1.z = f2bf(b.z * inv); h1.w = f2bf(b.w * inv);
    unsigned short* dst = fh + (size_t)prow * D + L * 8;
    *(ushort4*)dst = h0;
    *(ushort4*)(dst + 4) = h1;
}

// ---------------------------------------------------------------------------
// K2: banded positive stats v3 (unchanged).
// ---------------------------------------------------------------------------
__global__ __launch_bounds__(256) void k_posband3(
    const unsigned short* __restrict__ fh, const float* __restrict__ sqp,
    const int* __restrict__ labp, const int* __restrict__ cstart_g,
    const int* __restrict__ ccnt_g, float* __restrict__ meanpos, int Bn)
{
    __shared__ unsigned short SA[16 * 128];    // 4 KB per K-chunk
    __shared__ unsigned short SB[128 * 128];   // 32 KB per K-chunk
    __shared__ float sqr[16], rs[16];
    __shared__ int labr[16];
    __shared__ float sqc[128];
    __shared__ int labc[128];

    const int r0 = blockIdx.x * 16;
    const int tid = threadIdx.x, w = tid >> 6, L = tid & 63;
    const int lm = L & 15, ls = L >> 4;
    const int srow = L >> 4;      // 0..3 rows per gl16 group
    const int sseg = L & 15;      // 16-B seg slot within a 256 B row

    if (tid < 16) {
        labr[tid] = labp[r0 + tid];
        sqr[tid]  = sqp[r0 + tid];
        rs[tid]   = 0.f;
    }
    __syncthreads();
    const int c0 = cstart_g[labr[0]];
    const int c1 = cstart_g[labr[15]] + ccnt_g[labr[15]];

    for (int cc0 = c0; cc0 < c1; cc0 += 128) {
        __syncthreads();
        if (tid < 128) {
            int q = cc0 + tid;
            if (q < Bn) { sqc[tid] = sqp[q]; labc[tid] = labp[q]; }
            else        { sqc[tid] = 0.f;    labc[tid] = -1; }
        }
        float4v acc[2];
        acc[0] = (float4v){0.f, 0.f, 0.f, 0.f};
        acc[1] = (float4v){0.f, 0.f, 0.f, 0.f};

        for (int k0 = 0; k0 < D; k0 += 128) {
            __syncthreads();
            {   // SA: wave w stages rows w*4 .. w*4+3 (one gl16)
                int rmat = w * 4 + srow;
                int seg = sseg ^ (rmat & 15);
                gl16(fh + (size_t)(r0 + rmat) * D + k0 + seg * 8, &SA[(w * 4) * 128]);
            }
            #pragma unroll
            for (int it = 0; it < 8; ++it) {  // SB: 32 gl16 across 4 waves
                int rmat = it * 16 + w * 4 + srow;          // 0..127 (may over-read pad)
                int seg = sseg ^ (rmat & 15);
                gl16(fh + (size_t)(cc0 + rmat) * D + k0 + seg * 8,
                     &SB[(size_t)(it * 16 + w * 4) * 128]);
            }
            __syncthreads();
            #pragma unroll
            for (int h = 0; h < 4; ++h) {      // K=128 in 4 MFMA sub-steps
                int ra = lm;
                short8 af = *(const short8*)&SA[ra * 128 + (((h * 4 + ls) ^ (ra & 15))) * 8];
                #pragma unroll
                for (int ct = 0; ct < 2; ++ct) {
                    int rb = w * 32 + ct * 16 + lm;
                    short8 bf = *(const short8*)&SB[rb * 128 + (((h * 4 + ls) ^ (rb & 15))) * 8];
                    acc[ct] = __builtin_amdgcn_mfma_f32_16x16x32_bf16(af, bf, acc[ct], 0, 0, 0);
                }
            }
        }
        // epilogue: masked dist row-sums. C/D: row = ls*4+v, col = w*32+ct*16+lm
        #pragma unroll
        for (int v = 0; v < 4; ++v) {
            int ri = ls * 4 + v;
            int p = r0 + ri;
            int lr = labr[ri];
            float sr = sqr[ri];
            float sum = 0.f;
            #pragma unroll
            for (int ct = 0; ct < 2; ++ct) {
                int ci = w * 32 + ct * 16 + lm;
                int q = cc0 + ci;
                float d2 = sr + sqc[ci] - 2.0f * acc[ct][v];
                float dd = (d2 > 0.f) ? sqrtf(d2) : 0.f;
                sum += ((labc[ci] == lr) && (q != p)) ? dd : 0.f;
            }
            #pragma unroll
            for (int off = 8; off; off >>= 1) sum += __shfl_xor(sum, off, 64);
            if (lm == 0) atomicAdd(&rs[ri], sum);
        }
    }
    __syncthreads();
    if (tid < 16 && rs[tid] != 0.f) atomicAdd(&meanpos[r0 + tid], rs[tid]);
}

// ---------------------------------------------------------------------------
// K3 (R14): 256x256 tile, 8 waves (2Mx4N, wave=128x64, acc 8x4), fine 8-phase
// schedule (T3+T4 proper). Per K-tile (BK=64) group g, 4 phases:
//   p0: read B[k0](4) + A[mi0-3,k0](4); stage hf1(t[g+1]); 16 MFMA acc[0..3]
//   p1: read A[mi4-7,k0](4);            stage hf2(t[g+1]); 16 MFMA acc[4..7]
//   p2: read B[k1](4) + A[mi0-3,k1](4); stage hf3(t[g+1]); 16 MFMA acc[0..3]
//   p3: read A[mi4-7,k1](4); lgkmcnt(0); BARRIER (buf free);
//       stage hf0(t[g+2]); 16 MFMA acc[4..7]; vmcnt(2); BARRIER.
// Half-tile hf = 2x gl16/thread; hf0/1 = A rows 0-127/128-255, hf2/3 = B.
// t even->buf0, t odd->buf1; stages always target the buffer NOT being read
// (hf0 goes post-mid-barrier into the just-freed one). vmcnt(2) at each
// group end drains exactly tile t[g+1] and leaves hf0(t[g+2]) in flight —
// freshest drained load is >=1 phase old. Never vmcnt(0) until pipeline tail.
// sched_barrier(0) pins the per-phase interleave (m196: coarse split HURTS).
// Grid: 528 triangular blocks (=8*66, bijective XCD swizzle), 1 block/CU.
// ---------------------------------------------------------------------------
#define NKT 8           // K-tiles of BK=64 over D=512
#define BUFH 32768      // ushorts per buffer: A 16384 | B 16384 (64 KB)

__global__ __launch_bounds__(512, 2) void k_minsh_mfma(
    const unsigned short* __restrict__ fh, const float* __restrict__ sqp,
    const int* __restrict__ labp, const float* __restrict__ meanpos,
    const float* __restrict__ pcinv, unsigned* __restrict__ minbits)
{
    // --- XCD swizzle (528 = 8*66, bijective) + triangular decode ---
    int t = (blockIdx.x & 7) * 66 + (blockIdx.x >> 3);
    int I = (int)((sqrtf(8.0f * (float)t + 1.0f) - 1.0f) * 0.5f);
    while ((I + 1) * (I + 2) / 2 <= t) ++I;
    while (I * (I + 1) / 2 > t) --I;
    const int J = t - I * (I + 1) / 2;
    const int i0 = I * 256, j0 = J * 256;

    __shared__ unsigned short LA[2 * BUFH];                // 128 KB flat
    __shared__ float s_mp2r[256], s_sqr[256], s_mp2c[256], s_sqc[256];
    __shared__ int s_labr[256], s_labc[256];

    const int tid = threadIdx.x;
    const int w = tid >> 6, L = tid & 63;
    const int lm = L & 15, ls = L >> 4;
    const int wm = w >> 2, wn = w & 3;          // 2M x 4N wave grid
    const int u0 = ls ^ (lm & 7);               // k-step 0 swizzled segment
    const int u1 = u0 ^ 4;                      // k-step 1 ((4|ls)^swz, ls<4)

    // --- pre-swizzled staging sources: LDS[r][e] holds global seg e^(r&7) ---
    const unsigned short* srcA[4];
    const unsigned short* srcB[4];
    #pragma unroll
    for (int q = 0; q < 4; ++q) {
        int s = tid + 512 * q;                  // 16B slot 0..2047
        int r = s >> 3;                         // row 0..255
        int u = (s & 7) ^ (r & 7);              // global segment for this slot
        srcA[q] = fh + (size_t)(i0 + r) * D + u * 8;
        srcB[q] = fh + (size_t)(j0 + r) * D + u * 8;
    }
    unsigned short* LAm = &LA[0];
    const unsigned short* aB = LAm + (wm * 128 + lm) * 64;
    const unsigned short* bB = LAm + 16384 + (wn * 64 + lm) * 64;

    // half-tile stage: hf 0/1 = A rows 0-127/128-255, hf 2/3 = B (2x gl16)
#define STAGE_HF(t_, hf_) do {                                               \
    int ko_ = (t_) * 64;                                                     \
    unsigned short* db_ = LAm + ((t_) & 1) * BUFH + (((hf_) >= 2) ? 16384 : 0); \
    const unsigned short* const* sp_ = ((hf_) >= 2) ? srcB : srcA;           \
    int q0_ = ((hf_) & 1) * 2;                                               \
    gl16(sp_[q0_] + ko_,     db_ + (w * 64 + 512 * q0_) * 8);                \
    gl16(sp_[q0_ + 1] + ko_, db_ + (w * 64 + 512 * (q0_ + 1)) * 8);          \
} while (0)

#define MM16(mlo_)                                                           \
    __builtin_amdgcn_s_setprio(1);                                           \
    _Pragma("unroll")                                                        \
    for (int ni = 0; ni < 4; ++ni) {                                         \
        _Pragma("unroll")                                                    \
        for (int k = 0; k < 4; ++k)                                          \
            acc[(mlo_) + k][ni] = __builtin_amdgcn_mfma_f32_16x16x32_bf16(   \
                af[k], bf[ni], acc[(mlo_) + k][ni], 0, 0, 0);                 \
    }                                                                        \
    __builtin_amdgcn_s_setprio(0);

    // GROUP body: co_ = (g&1)*BUFH; DO1 = stage hf1-3(t[g+1]); DO0 = stage
    // hf0(t[g+2]); WAITK = 2 (steady), 0 (g==NKT-2), -1 (last, no end bar)
#define GROUP(co_, g_, DO1_, DO0_, WAITK_) do {                              \
    short8 af[4], bf[4];                                                     \
    /* p0 */                                                                 \
    _Pragma("unroll")                                                        \
    for (int ni = 0; ni < 4; ++ni) bf[ni] = *(const short8*)(bB + (co_) + ni * 1024 + u0 * 8); \
    _Pragma("unroll")                                                        \
    for (int k = 0; k < 4; ++k)  af[k] = *(const short8*)(aB + (co_) + k * 1024 + u0 * 8); \
    if (DO1_) STAGE_HF((g_) + 1, 1);                                         \
    MM16(0);                                                                 \
    __builtin_amdgcn_sched_barrier(0);                                       \
    /* p1 */                                                                 \
    _Pragma("unroll")                                                        \
    for (int k = 0; k < 4; ++k)  af[k] = *(const short8*)(aB + (co_) + (4 + k) * 1024 + u0 * 8); \
    if (DO1_) STAGE_HF((g_) + 1, 2);                                         \
    MM16(4);                                                                 \
    __builtin_amdgcn_sched_barrier(0);                                       \
    /* p2 */                                                                 \
    _Pragma("unroll")                                                        \
    for (int ni = 0; ni < 4; ++ni) bf[ni] = *(const short8*)(bB + (co_) + ni * 1024 + u1 * 8); \
    _Pragma("unroll")                                                        \
    for (int k = 0; k < 4; ++k)  af[k] = *(const short8*)(aB + (co_) + k * 1024 + u1 * 8); \
    if (DO1_) STAGE_HF((g_) + 1, 3);                                         \
    MM16(0);                                                                 \
    __builtin_amdgcn_sched_barrier(0);                                       \
    /* p3 */                                                                 \
    _Pragma("unroll")                                                        \
    for (int k = 0; k < 4; ++k)  af[k] = *(const short8*)(aB + (co_) + (4 + k) * 1024 + u1 * 8); \
    asm volatile("s_waitcnt lgkmcnt(0)" ::: "memory");                       \
    __builtin_amdgcn_sched_barrier(0);                                       \
    __builtin_amdgcn_s_barrier();          /* buf[g&1] free for overwrite */ \
    __builtin_amdgcn_sched_barrier(0);                                       \
    if (DO0_) STAGE_HF((g_) + 2, 0);                                         \
    MM16(4);                                                                 \
    if ((WAITK_) == 2)      { asm volatile("s_waitcnt vmcnt(2)" ::: "memory"); } \
    else if ((WAITK_) == 0) { asm volatile("s_waitcnt vmcnt(0)" ::: "memory"); } \
    __builtin_amdgcn_sched_barrier(0);                                       \
    if ((WAITK_) >= 0) {                                                     \
        __builtin_amdgcn_s_barrier();      /* tile t[g+1] visible to all */  \
        __builtin_amdgcn_sched_barrier(0);                                   \
    }                                                                        \
} while (0)

    // --- metadata first (loads consumed before stages; pinned by sched_barrier)
    if (tid < 256) {
        int p = i0 + tid;
        float mp = meanpos[p] * pcinv[p];
        s_mp2r[tid] = mp * mp;
        s_sqr[tid]  = sqp[p];
        s_labr[tid] = labp[p];
    } else {
        int q = tid - 256, p = j0 + q;
        float mp = meanpos[p] * pcinv[p];
        s_mp2c[q] = mp * mp;
        s_sqc[q]  = sqp[p];
        s_labc[q] = labp[p];
    }
    __builtin_amdgcn_sched_barrier(0);

    float4v acc[8][4];
    #pragma unroll
    for (int mi = 0; mi < 8; ++mi)
        #pragma unroll
        for (int ni = 0; ni < 4; ++ni) acc[mi][ni] = (float4v){0.f, 0.f, 0.f, 0.f};

    // --- prologue: t0 full (8 loads) + hf0(t1) (2); wait t0 only ---
    STAGE_HF(0, 0); STAGE_HF(0, 1); STAGE_HF(0, 2); STAGE_HF(0, 3);
    STAGE_HF(1, 0);
    asm volatile("s_waitcnt vmcnt(2)" ::: "memory");   // t0 landed; hf0(t1) in flight
    __builtin_amdgcn_sched_barrier(0);
    __builtin_amdgcn_s_barrier();
    __builtin_amdgcn_sched_barrier(0);

    // --- 8 groups: 0..5 uniform (stage next tile, vmcnt(2)); 6,7 peeled ---
    #pragma unroll
    for (int g = 0; g < NKT - 2; ++g) {
        const int co = (g & 1) * BUFH;
        GROUP(co, g, true, true, 2);
    }
    GROUP(((NKT - 2) & 1) * BUFH, NKT - 2, true,  false, 0);   // g=6: finish t7 loads
    GROUP(((NKT - 1) & 1) * BUFH, NKT - 1, false, false, -1);  // g=7: drain, no stages

#undef GROUP
#undef MM16
#undef STAGE_HF

    // --- epilogue: dual-side semi-hard mins, LDS-combined ---
    // C/D: row = wm*128 + mi*16 + ls*4 + v, col = wn*64 + ni*16 + lm
    unsigned* rminb = (unsigned*)&LA[0];        // LA dead; reuse
    unsigned* cminb = rminb + 256;
    __syncthreads();
    if (tid < 256) rminb[tid] = INF_BITS;
    else           cminb[tid - 256] = INF_BITS;
    __syncthreads();

    const float INFF = __uint_as_float(INF_BITS);
    float sc[4], mp2c[4]; int lc[4];
    #pragma unroll
    for (int ni = 0; ni < 4; ++ni) {
        int cl = wn * 64 + ni * 16 + lm;
        sc[ni]   = s_sqc[cl];
        mp2c[ni] = s_mp2c[cl];
        lc[ni]   = s_labc[cl];
    }
    float vminc[4];
    #pragma unroll
    for (int ni = 0; ni < 4; ++ni) vminc[ni] = INFF;

    #pragma unroll
    for (int mi = 0; mi < 8; ++mi) {
        #pragma unroll
        for (int v = 0; v < 4; ++v) {
            int rl = wm * 128 + mi * 16 + ls * 4 + v;
            float mp2r = s_mp2r[rl];
            float sr   = s_sqr[rl];
            int   li   = s_labr[rl];
            float vminr = INFF;
            #pragma unroll
            for (int ni = 0; ni < 4; ++ni) {
                float d2 = fmaf(-2.0f, acc[mi][ni][v], sr + sc[ni]);
                bool neq = (li != lc[ni]);
                vminr     = fminf(vminr,     (neq && d2 > mp2r)     ? d2 : INFF);
                vminc[ni] = fminf(vminc[ni], (neq && d2 > mp2c[ni]) ? d2 : INFF);
            }
            #pragma unroll
            for (int off = 8; off; off >>= 1)
                vminr = fminf(vminr, __shfl_xor(vminr, off, 64));
            if (lm == 0 && __float_as_uint(vminr) != INF_BITS)
                atomicMin(&rminb[rl], __float_as_uint(vminr));
        }
    }
    #pragma unroll
    for (int ni = 0; ni < 4; ++ni) {
        float vc = vminc[ni];
        vc = fminf(vc, __shfl_xor(vc, 16, 64));
        vc = fminf(vc, __shfl_xor(vc, 32, 64));
        if (ls == 0 && __float_as_uint(vc) != INF_BITS)
            atomicMin(&cminb[wn * 64 + ni * 16 + lm], __float_as_uint(vc));
    }
    __syncthreads();
    if (tid < 256) {
        unsigned rb = rminb[tid];
        if (rb != INF_BITS) atomicMin(&minbits[i0 + tid], rb);
    } else if (i0 != j0) {
        unsigned cb = cminb[tid - 256];
        if (cb != INF_BITS) atomicMin(&minbits[j0 + tid - 256], cb);
    }
}

// ---------------------------------------------------------------------------
// K4: final reduction (unchanged).
// ---------------------------------------------------------------------------
__global__ __launch_bounds__(1024) void k_finish(const float* __restrict__ meanpos,
        const float* __restrict__ pcinv, const int* __restrict__ poscnt,
        const unsigned* __restrict__ minbits, float* __restrict__ out, int Bn) {
    float lsum = 0.f; int lcnt = 0;
    for (int i = threadIdx.x; i < Bn; i += 1024) {
        int pc = poscnt[i];
        bool valid = (pc > 1) && (pc < Bn);
        unsigned mb = minbits[i];
        if (valid && mb != INF_BITS) {
            float v = fmaf(meanpos[i], pcinv[i], MARGIN - sqrtf(__uint_as_float(mb)));
            lsum += (v > 0.f) ? v : 0.f;
            lcnt += 1;
        }
    }
    __shared__ float ssum[16]; __shared__ int scnt[16];
    int lane = threadIdx.x & 63, wid = threadIdx.x >> 6;
    #pragma unroll
    for (int off = 32; off; off >>= 1) {
        lsum += __shfl_down(lsum, off, 64);
        lcnt += __shfl_down(lcnt, off, 64);
    }
    if (lane == 0) { ssum[wid] = lsum; scnt[wid] = lcnt; }
    __syncthreads();
    if (threadIdx.x == 0) {
        float s = 0.f; int c = 0;
        #pragma unroll
        for (int q = 0; q < 16; ++q) { s += ssum[q]; c += scnt[q]; }
        out[0] = (c > 0) ? s / (float)c : 0.f;
    }
}

// ---------------------------------------------------------------------------
extern "C" void kernel_launch(void* const* d_in, const int* in_sizes, int n_in,
                              void* d_out, int out_size, void* d_ws, size_t ws_size,
                              hipStream_t stream) {
    const float* x = (const float*)d_in[0];
    const int* lab = (const int*)d_in[1];
    int Bn = in_sizes[1];                 // 8192; D fixed at 512

    size_t nd = (size_t)(Bn + PADR) * D;  // padded for banded over-read (K2)
    unsigned short* fh = (unsigned short*)d_ws;
    float* sqp        = (float*)(fh + nd);
    float* meanpos    = sqp + Bn;         // raw dist-sums
    float* pcinv      = meanpos + Bn;
    int* poscnt       = (int*)(pcinv + Bn);
    unsigned* minbits = (unsigned*)(poscnt + Bn);
    int* pos          = (int*)(minbits + Bn);
    int* labp         = pos + Bn;
    int* cstart_g     = labp + Bn;
    int* ccnt_g       = cstart_g + NCLS;

    k_bucket<<<1, 1024, 0, stream>>>(lab, Bn, pos, labp, cstart_g, ccnt_g,
                                     meanpos, pcinv, poscnt, minbits);
    k_normalize<<<Bn / 4, 256, 0, stream>>>(x, pos, fh, sqp);
    k_posband3<<<Bn / 16, 256, 0, stream>>>(fh, sqp, labp, cstart_g, ccnt_g,
                                            meanpos, Bn);
    int nbr = Bn / 256;                   // 32 row-tiles
    int T = nbr * (nbr + 1) / 2;          // 528 triangular 256x256 tiles
    k_minsh_mfma<<<T, 512, 0, stream>>>(fh, sqp, labp, meanpos, pcinv, minbits);
    k_finish<<<1, 1024, 0, stream>>>(meanpos, pcinv, poscnt, minbits,
                                     (float*)d_out, Bn);
}